// Round 6
// baseline (152.307 us; speedup 1.0000x reference)
//
#include <hip/hip_runtime.h>

typedef float f32x4 __attribute__((ext_vector_type(4)));
typedef unsigned int u32x4 __attribute__((ext_vector_type(4)));
typedef unsigned int u32x2 __attribute__((ext_vector_type(2)));
typedef __bf16 bf16x8 __attribute__((ext_vector_type(8)));

// ---------------- LDS layout (bytes) ----------------
#define LDS_ACT   0        // [128][136] bf16 : 34816  (m1 [slot][k]; tail f32 scratch)
#define LDS_MBUF  34816    // [128][132] bf16 : 33792  (Hjs tile -> masked m, [slot][d])
#define LDS_EBUF  68608    // [128][40]  bf16 : 10240  (eattr tile [slot][k])
#define LDS_FP    78848    // 1024 f32 : 4096
// fp floats: dsq 0, vmask 128, rel 256 (384), bc1s 640, wc2s 768, hrow 896
#define LDS_CIDX  82944    // int: cidx 384, wcnt 8, wsc 9 -> 1604 B
#define LDS_BYTES 84608
// setup-only overlays (dead once weight frags are in VGPRs):
//   W2T  @ 0      [128][136] bf16 (34816)
//   WC1T @ 34816  [128][136] bf16 (34816, spills into ebuf region: ok)
//   WET  @ 69632  [128][40]  bf16 (10240, spills into fp[0..255]: ok)

__device__ __forceinline__ unsigned short f2bf(float f) {
  unsigned int u = __builtin_bit_cast(unsigned int, f);
  unsigned int r = u + 0x7FFFu + ((u >> 16) & 1u);
  return (unsigned short)(r >> 16);
}
__device__ __forceinline__ float bf2f(unsigned short hbits) {
  unsigned int u = ((unsigned int)hbits) << 16;
  return __builtin_bit_cast(float, u);
}
__device__ __forceinline__ unsigned int pk2(float lo, float hi) {
  return (unsigned int)f2bf(lo) | ((unsigned int)f2bf(hi) << 16);
}
__device__ __forceinline__ float silu_f(float xv) {
  float t = __builtin_amdgcn_exp2f(-1.44269504088896f * xv);  // exp(-x)
  return xv * __builtin_amdgcn_rcpf(1.0f + t);
}
__device__ __forceinline__ f32x4 mfma16(u32x4 a, u32x4 b, f32x4 c) {
  return __builtin_amdgcn_mfma_f32_16x16x32_bf16(
      __builtin_bit_cast(bf16x8, a), __builtin_bit_cast(bf16x8, b), c, 0, 0, 0);
}

// ---- precompute: his = h@W1[0:128]+b1 (f32), hjw = bf16(h@W1[128:256]) ----
__global__ void egnn_pre(const float* __restrict__ h,
                         const float* __restrict__ msg_w1,
                         const float* __restrict__ msg_b1,
                         float* __restrict__ his,
                         unsigned short* __restrict__ hjw) {
  __shared__ float hr[128];
  const int row = blockIdx.x;      // b*384+n
  const int t = threadIdx.x;       // 0..255
  if (t < 128) hr[t] = h[(size_t)row*128 + t];
  __syncthreads();
  const int col = t & 127;
  const int base = (t < 128) ? 0 : 128;
  float s = (t < 128) ? msg_b1[col] : 0.0f;
  #pragma unroll 4
  for (int k = 0; k < 128; ++k) s += hr[k] * msg_w1[(size_t)(base + k)*128 + col];
  if (t < 128) his[(size_t)row*128 + col] = s;
  else         hjw[(size_t)row*128 + col] = f2bf(s);
}

// ---------------- fused main kernel: one block per (b,i) ----------------
__launch_bounds__(512, 1)
__global__ void egnn_main(
    const float* __restrict__ h, const float* __restrict__ x,
    const float* __restrict__ eattr, const float* __restrict__ amask,
    const float* __restrict__ msg_w1, const float* __restrict__ msg_w2,
    const float* __restrict__ msg_b2, const float* __restrict__ node_w1,
    const float* __restrict__ node_b1, const float* __restrict__ node_w2,
    const float* __restrict__ node_b2, const float* __restrict__ coord_w1,
    const float* __restrict__ coord_b1, const float* __restrict__ coord_w2,
    const float* __restrict__ ln_g, const float* __restrict__ ln_b,
    const int* __restrict__ adj, const float* __restrict__ his,
    const unsigned short* __restrict__ hjw, float* __restrict__ out)
{
  extern __shared__ char smem[];
  short* act  = (short*)(smem + LDS_ACT);
  short* mbuf = (short*)(smem + LDS_MBUF);
  short* ebuf = (short*)(smem + LDS_EBUF);
  float* fp   = (float*)(smem + LDS_FP);
  float* dsq  = fp;          float* vmask = fp + 128;
  float* rel  = fp + 256;    float* bc1s  = fp + 640;
  float* wc2s = fp + 768;    float* hrow  = fp + 896;
  int*   cidx = (int*)(smem + LDS_CIDX);
  int*   wcnt = cidx + 384;
  int*   wsc  = cidx + 392;  // [0..7] offsets, [8] = deg

  const int tid  = threadIdx.x;
  const int bi   = blockIdx.x;            // b*384 + i
  const int bb   = (bi / 384) * 384;
  const int wave = tid >> 6;
  const int lane = tid & 63;
  const int g    = lane >> 4;
  const int lr   = lane & 15;
  const int R  = wave * 16;               // GEMM1 d-rows / GEMM3 j-slot block
  const int RB = (wave >> 1) * 32;        // GEMM2 d-rows
  const int CB = (wave & 1) * 64;         // GEMM2 j-slot cols
  const int d4 = R + 4*g;                 // GEMM1: this lane's 4 consecutive d
  const int jW = R + lr;                  // GEMM3: this lane's j-slot

  // ---- adjacency ballot ----
  const bool pred = (tid < 384) && (adj[(size_t)bi*384 + tid] != 0);
  const unsigned long long bmask = __ballot(pred);
  if (lane == 0) wcnt[wave] = __popcll(bmask);

  // ---- stage weight overlays (bf16, [out_d][k]) ----
  short* w2o  = (short*)(smem + 0);
  short* wc1o = (short*)(smem + 34816);
  short* weo  = (short*)(smem + 69632);
  for (int idx = tid; idx < 32*128; idx += 512) {
    int k = idx >> 7, d = idx & 127;
    weo[d*40 + k] = (short)f2bf(msg_w1[(size_t)(256 + k)*128 + d]);
  }
  for (int idx = tid; idx < 128*128; idx += 512) {
    int k = idx >> 7, d = idx & 127;
    w2o[d*136 + k]  = (short)f2bf(msg_w2[idx]);
    wc1o[d*136 + k] = (short)f2bf(coord_w1[idx]);
  }
  __syncthreads();

  // ---- scan (tid 0) + read weight fragments to VGPRs ----
  if (tid == 0) {
    int run = 0;
    #pragma unroll
    for (int w = 0; w < 8; ++w) { wsc[w] = run; run += wcnt[w]; }
    wsc[8] = run;
  }
  const u32x4 aw = *(const u32x4*)(weo + (R + lr)*40 + g*8);
  u32x4 w2f0[4], w2f1[4];
  #pragma unroll
  for (int kk = 0; kk < 4; ++kk) {
    w2f0[kk] = *(const u32x4*)(w2o + (RB + lr)*136 + kk*32 + g*8);
    w2f1[kk] = *(const u32x4*)(w2o + (RB + 16 + lr)*136 + kk*32 + g*8);
  }
  u32x4 wc1f[8][4];
  #pragma unroll
  for (int rf = 0; rf < 8; ++rf)
    #pragma unroll
    for (int kk = 0; kk < 4; ++kk)
      wc1f[rf][kk] = *(const u32x4*)(wc1o + (rf*16 + lr)*136 + kk*32 + g*8);
  __syncthreads();   // overlays consumed; scan visible

  // ---- write compacted index list + small constants ----
  if (pred) {
    int rank = __popcll(bmask & ((1ull << lane) - 1ull));
    cidx[wsc[wave] + rank] = tid;
  }
  if (tid < 128) {
    bc1s[tid] = coord_b1[tid];
    wc2s[tid] = coord_w2[tid];
    hrow[tid] = h[(size_t)bi*128 + tid];
  }
  const int deg = wsc[8];
  // per-lane constants (fixed d-ranges across chunks)
  const float4 His4 = *(const float4*)(his + (size_t)bi*128 + d4);
  const float4 wd4  = *(const float4*)(msg_w1 + 288*128 + d4);
  const float4 b2a  = *(const float4*)(msg_b2 + RB + 4*g);
  const float4 b2b  = *(const float4*)(msg_b2 + RB + 16 + 4*g);
  const float xi0 = x[bi*3+0], xi1 = x[bi*3+1], xi2 = x[bi*3+2];
  float hacc_v[8];
  #pragma unroll
  for (int v = 0; v < 8; ++v) hacc_v[v] = 0.0f;
  float xc0 = 0.0f, xc1 = 0.0f, xc2 = 0.0f;
  __syncthreads();   // cidx + constants visible

  const int nchunk = (deg + 127) >> 7;
  for (int ch = 0; ch < nchunk; ++ch) {
    const int j0 = ch * 128;
    // ---- stage: gathered Hjs tile, gathered eattr tile, geometry ----
    #pragma unroll
    for (int it = 0; it < 4; ++it) {
      int idx = tid + it*512;
      int r = idx >> 4, s = idx & 15;
      int t = j0 + r;
      int cj = (t < deg) ? cidx[t] : 0;
      u32x4 v = *(const u32x4*)(hjw + ((size_t)(bb + cj))*128 + s*8);
      *(u32x2*)(mbuf + r*132 + s*8)     = (u32x2){v[0], v[1]};
      *(u32x2*)(mbuf + r*132 + s*8 + 4) = (u32x2){v[2], v[3]};
    }
    #pragma unroll
    for (int it = 0; it < 2; ++it) {
      int idx = tid + it*512;
      int j = idx >> 3, s = idx & 7;
      int t = j0 + j;
      int cj = (t < deg) ? cidx[t] : 0;
      float4 p = *(const float4*)(eattr + ((size_t)bi*384 + cj)*32 + s*4);
      *(u32x2*)(ebuf + j*40 + s*4) = (u32x2){pk2(p.x, p.y), pk2(p.z, p.w)};
    }
    if (tid < 128) {
      int t = j0 + tid;
      int cj = (t < deg) ? cidx[t] : 0;
      float r0 = xi0 - x[(bb + cj)*3 + 0];
      float r1 = xi1 - x[(bb + cj)*3 + 1];
      float r2 = xi2 - x[(bb + cj)*3 + 2];
      rel[tid*3+0] = r0; rel[tid*3+1] = r1; rel[tid*3+2] = r2;
      dsq[tid]   = r0*r0 + r1*r1 + r2*r2;
      vmask[tid] = (t < deg) ? 1.0f : 0.0f;
    }
    __syncthreads();

    // ---- GEMM1 (C^T): act[slot][d] = silu(We^T x eattr + init) ----
    {
      #pragma unroll
      for (int cf = 0; cf < 8; ++cf) {
        const int j = cf*16 + lr;
        u32x4 be = *(const u32x4*)(ebuf + j*40 + g*8);
        u32x2 hj = *(const u32x2*)(mbuf + j*132 + d4);
        const float dq = dsq[j];
        f32x4 acc;
        acc[0] = His4.x + dq*wd4.x + bf2f((unsigned short)(hj[0] & 0xFFFFu));
        acc[1] = His4.y + dq*wd4.y + bf2f((unsigned short)(hj[0] >> 16));
        acc[2] = His4.z + dq*wd4.z + bf2f((unsigned short)(hj[1] & 0xFFFFu));
        acc[3] = His4.w + dq*wd4.w + bf2f((unsigned short)(hj[1] >> 16));
        acc = mfma16(aw, be, acc);
        *(u32x2*)(act + j*136 + d4) =
            (u32x2){pk2(silu_f(acc[0]), silu_f(acc[1])),
                    pk2(silu_f(acc[2]), silu_f(acc[3]))};
      }
    }
    __syncthreads();

    // ---- GEMM2 (C^T): m[slot][d] = silu(W2^T x m1 + b2)*vmask; hacc in-reg ----
    {
      f32x4 acc2[2][4];
      #pragma unroll
      for (int cf = 0; cf < 4; ++cf) {
        acc2[0][cf] = (f32x4){b2a.x, b2a.y, b2a.z, b2a.w};
        acc2[1][cf] = (f32x4){b2b.x, b2b.y, b2b.z, b2b.w};
      }
      #pragma unroll
      for (int kk = 0; kk < 4; ++kk) {
        #pragma unroll
        for (int cf = 0; cf < 4; ++cf) {
          u32x4 bfr = *(const u32x4*)(act + (CB + cf*16 + lr)*136 + kk*32 + g*8);
          acc2[0][cf] = mfma16(w2f0[kk], bfr, acc2[0][cf]);
          acc2[1][cf] = mfma16(w2f1[kk], bfr, acc2[1][cf]);
        }
      }
      #pragma unroll
      for (int cf = 0; cf < 4; ++cf) {
        const int j = CB + cf*16 + lr;
        const float aj = vmask[j];
        #pragma unroll
        for (int rf = 0; rf < 2; ++rf) {
          float v0 = silu_f(acc2[rf][cf][0]) * aj;
          float v1 = silu_f(acc2[rf][cf][1]) * aj;
          float v2 = silu_f(acc2[rf][cf][2]) * aj;
          float v3 = silu_f(acc2[rf][cf][3]) * aj;
          hacc_v[rf*4+0] += v0; hacc_v[rf*4+1] += v1;
          hacc_v[rf*4+2] += v2; hacc_v[rf*4+3] += v3;
          *(u32x2*)(mbuf + j*132 + RB + rf*16 + 4*g) =
              (u32x2){pk2(v0, v1), pk2(v2, v3)};
        }
      }
    }
    __syncthreads();

    // ---- GEMM3 (C^T): c1[d][slot]; cw via in-wave g-reduce; xc in-reg ----
    {
      f32x4 acc3[8];
      #pragma unroll
      for (int rf = 0; rf < 8; ++rf)
        acc3[rf] = *(const f32x4*)(bc1s + rf*16 + 4*g);
      #pragma unroll
      for (int kk = 0; kk < 4; ++kk) {
        u32x2 blo = *(const u32x2*)(mbuf + jW*132 + kk*32 + g*8);
        u32x2 bhi = *(const u32x2*)(mbuf + jW*132 + kk*32 + g*8 + 4);
        u32x4 bm = (u32x4){blo[0], blo[1], bhi[0], bhi[1]};
        #pragma unroll
        for (int rf = 0; rf < 8; ++rf)
          acc3[rf] = mfma16(wc1f[rf][kk], bm, acc3[rf]);
      }
      float cwp = 0.0f;
      #pragma unroll
      for (int rf = 0; rf < 8; ++rf) {
        f32x4 wv = *(const f32x4*)(wc2s + rf*16 + 4*g);
        cwp += silu_f(acc3[rf][0]) * wv[0];
        cwp += silu_f(acc3[rf][1]) * wv[1];
        cwp += silu_f(acc3[rf][2]) * wv[2];
        cwp += silu_f(acc3[rf][3]) * wv[3];
      }
      cwp += __shfl_xor(cwp, 16, 64);
      cwp += __shfl_xor(cwp, 32, 64);
      if (lane < 16) {
        const float dist = sqrtf(dsq[jW] + 1e-8f);
        const float f = cwp * __builtin_amdgcn_rcpf(dist + 1.0f) * vmask[jW];
        xc0 += f * rel[jW*3+0];
        xc1 += f * rel[jW*3+1];
        xc2 += f * rel[jW*3+2];
      }
    }
    __syncthreads();
  }

  // ---- tail: hacc reduce (shuffle over lr) + xc publish ----
  #pragma unroll
  for (int v = 0; v < 8; ++v) {
    hacc_v[v] += __shfl_xor(hacc_v[v], 1, 64);
    hacc_v[v] += __shfl_xor(hacc_v[v], 2, 64);
    hacc_v[v] += __shfl_xor(hacc_v[v], 4, 64);
    hacc_v[v] += __shfl_xor(hacc_v[v], 8, 64);
  }
  float* actF  = (float*)act;     // act dead; reuse as f32 scratch
  float* hpart = actF;            // 256
  float* xcf   = actF + 256;      // 384
  float* red   = actF + 640;      // 512
  float* hagg  = actF + 1152;     // 128
  float* uvec  = actF + 1280;     // 128
  float* lnr   = actF + 1408;     // 4
  if (lr == 0) {
    #pragma unroll
    for (int rf = 0; rf < 2; ++rf)
      #pragma unroll
      for (int r = 0; r < 4; ++r)
        hpart[(wave & 1)*128 + RB + rf*16 + 4*g + r] = hacc_v[rf*4 + r];
  }
  if (lane < 16) {
    xcf[jW] = xc0; xcf[128 + jW] = xc1; xcf[256 + jW] = xc2;
  }
  __syncthreads();
  if (tid < 128) hagg[tid] = hpart[tid] + hpart[128 + tid];
  if (tid < 3) {
    float sx = 0.0f;
    #pragma unroll 8
    for (int j = 0; j < 128; ++j) sx += xcf[tid*128 + j];
    out[98304 + (size_t)bi*3 + tid] = x[bi*3 + tid] + sx * amask[bi];
  }
  __syncthreads();

  // ---- node MLP layer 1: u = silu([h, hagg] @ node_w1 + b1) ----
  {
    const int d = tid & 127, q = tid >> 7;
    float s = 0.0f;
    for (int k = q*64; k < q*64 + 64; ++k) {
      const float inv = (k < 128) ? hrow[k] : hagg[k - 128];
      s += inv * node_w1[(size_t)k*128 + d];
    }
    red[q*128 + d] = s;
  }
  __syncthreads();
  if (tid < 128)
    uvec[tid] = silu_f(red[tid] + red[128+tid] + red[256+tid] + red[384+tid] + node_b1[tid]);
  __syncthreads();

  // ---- node MLP layer 2 + residual ----
  {
    const int d = tid & 127, q = tid >> 7;
    float s = 0.0f;
    for (int k = q*32; k < q*32 + 32; ++k) s += uvec[k] * node_w2[(size_t)k*128 + d];
    red[q*128 + d] = s;
  }
  __syncthreads();
  float y = 0.0f;
  if (tid < 128)
    y = hrow[tid] + red[tid] + red[128+tid] + red[256+tid] + red[384+tid] + node_b2[tid];

  // ---- LayerNorm across 128 values (2 waves active) ----
  float ssum = (tid < 128) ? y : 0.0f;
  #pragma unroll
  for (int mm = 1; mm < 64; mm <<= 1) ssum += __shfl_xor(ssum, mm, 64);
  if (tid < 128 && lane == 0) lnr[wave] = ssum;
  __syncthreads();
  const float mu = (lnr[0] + lnr[1]) * (1.0f/128.0f);
  float yc = (tid < 128) ? (y - mu) : 0.0f;
  float sq = yc * yc;
  #pragma unroll
  for (int mm = 1; mm < 64; mm <<= 1) sq += __shfl_xor(sq, mm, 64);
  if (tid < 128 && lane == 0) lnr[2 + wave] = sq;
  __syncthreads();
  if (tid < 128) {
    const float var = (lnr[2] + lnr[3]) * (1.0f/128.0f);
    out[(size_t)bi*128 + tid] = yc * rsqrtf(var + 1e-3f) * ln_g[tid] + ln_b[tid];
  }
}

extern "C" void kernel_launch(void* const* d_in, const int* in_sizes, int n_in,
                              void* d_out, int out_size, void* d_ws, size_t ws_size,
                              hipStream_t stream) {
  const float* h        = (const float*)d_in[0];
  const float* x        = (const float*)d_in[1];
  const float* eattr    = (const float*)d_in[2];
  const float* amask    = (const float*)d_in[3];
  const float* msg_w1   = (const float*)d_in[4];
  const float* msg_b1   = (const float*)d_in[5];
  const float* msg_w2   = (const float*)d_in[6];
  const float* msg_b2   = (const float*)d_in[7];
  const float* node_w1  = (const float*)d_in[8];
  const float* node_b1  = (const float*)d_in[9];
  const float* node_w2  = (const float*)d_in[10];
  const float* node_b2  = (const float*)d_in[11];
  const float* coord_w1 = (const float*)d_in[12];
  const float* coord_b1 = (const float*)d_in[13];
  const float* coord_w2 = (const float*)d_in[14];
  const float* ln_g     = (const float*)d_in[15];
  const float* ln_b     = (const float*)d_in[16];
  const int*   adj      = (const int*)d_in[17];
  float* out = (float*)d_out;
  float* his = (float*)d_ws;                                        // 768*128*4
  unsigned short* hjw = (unsigned short*)((char*)d_ws + 393216);    // 768*128*2

  hipFuncSetAttribute((const void*)egnn_main,
                      hipFuncAttributeMaxDynamicSharedMemorySize, LDS_BYTES);

  egnn_pre<<<768, 256, 0, stream>>>(h, msg_w1, msg_b1, his, hjw);
  egnn_main<<<768, 512, LDS_BYTES, stream>>>(h, x, eattr, amask, msg_w1, msg_w2,
      msg_b2, node_w1, node_b1, node_w2, node_b2, coord_w1, coord_b1, coord_w2,
      ln_g, ln_b, adj, his, hjw, out);
}

// Round 7
// 142.503 us; speedup vs baseline: 1.0688x; 1.0688x over previous
//
#include <hip/hip_runtime.h>

typedef float f32x4 __attribute__((ext_vector_type(4)));
typedef unsigned int u32x4 __attribute__((ext_vector_type(4)));
typedef unsigned int u32x2 __attribute__((ext_vector_type(2)));
typedef __bf16 bf16x8 __attribute__((ext_vector_type(8)));

// ---------------- LDS layout (bytes) ----------------
// permanent:
#define LDS_ACT    0        // [128][136] bf16 : 34816 (m1 [slot][k]; tail f32 scratch)
#define LDS_MBUF   34816    // [128][132] bf16 : 33792 (m [slot][d])
#define LDS_FP     68608    // 640 f32 : 2560 (dsq 0, vmask 128, coef 256..639)
#define LDS_CIDX   71168    // 384 u16 : 768
// setup overlays (dead after weight frags move to VGPRs):
//   W2o  @ 0      [128][136] bf16 (34816)  — act region
//   WC1o @ 34816  [128][132] bf16 (33792)  — mbuf region
//   WEo  @ 68608  [128][40]  bf16 (10240)  — covers fp+cidx region -> 78848
#define LDS_WCNT   78848    // 8 ints + 9 ints (never overlapped)
#define LDS_BYTES  78944    // x2 blocks = 157888 <= 163840

__device__ __forceinline__ unsigned short f2bf(float f) {
  unsigned int u = __builtin_bit_cast(unsigned int, f);
  unsigned int r = u + 0x7FFFu + ((u >> 16) & 1u);
  return (unsigned short)(r >> 16);
}
__device__ __forceinline__ float bf2f(unsigned short hbits) {
  unsigned int u = ((unsigned int)hbits) << 16;
  return __builtin_bit_cast(float, u);
}
__device__ __forceinline__ unsigned int pk2(float lo, float hi) {
  return (unsigned int)f2bf(lo) | ((unsigned int)f2bf(hi) << 16);
}
__device__ __forceinline__ float silu_f(float xv) {
  float t = __builtin_amdgcn_exp2f(-1.44269504088896f * xv);  // exp(-x)
  return xv * __builtin_amdgcn_rcpf(1.0f + t);
}
__device__ __forceinline__ f32x4 mfma16(u32x4 a, u32x4 b, f32x4 c) {
  return __builtin_amdgcn_mfma_f32_16x16x32_bf16(
      __builtin_bit_cast(bf16x8, a), __builtin_bit_cast(bf16x8, b), c, 0, 0, 0);
}

// ---- precompute: his = h@W1[0:128]+b1 (f32), hjw = bf16(h@W1[128:256]) ----
__global__ void egnn_pre(const float* __restrict__ h,
                         const float* __restrict__ msg_w1,
                         const float* __restrict__ msg_b1,
                         float* __restrict__ his,
                         unsigned short* __restrict__ hjw) {
  __shared__ float hr[128];
  const int row = blockIdx.x;      // b*384+n
  const int t = threadIdx.x;       // 0..255
  if (t < 128) hr[t] = h[(size_t)row*128 + t];
  __syncthreads();
  const int col = t & 127;
  const int base = (t < 128) ? 0 : 128;
  float s = (t < 128) ? msg_b1[col] : 0.0f;
  #pragma unroll 4
  for (int k = 0; k < 128; ++k) s += hr[k] * msg_w1[(size_t)(base + k)*128 + col];
  if (t < 128) his[(size_t)row*128 + col] = s;
  else         hjw[(size_t)row*128 + col] = f2bf(s);
}

// ---------------- fused main kernel: one block per (b,i), 2 blocks/CU ----------------
__launch_bounds__(512, 4)
__global__ void egnn_main(
    const float* __restrict__ h, const float* __restrict__ x,
    const float* __restrict__ eattr, const float* __restrict__ amask,
    const float* __restrict__ msg_w1, const float* __restrict__ msg_w2,
    const float* __restrict__ msg_b2, const float* __restrict__ node_w1,
    const float* __restrict__ node_b1, const float* __restrict__ node_w2,
    const float* __restrict__ node_b2, const float* __restrict__ coord_w1,
    const float* __restrict__ coord_b1, const float* __restrict__ coord_w2,
    const float* __restrict__ ln_g, const float* __restrict__ ln_b,
    const int* __restrict__ adj, const float* __restrict__ his,
    const unsigned short* __restrict__ hjw, float* __restrict__ out)
{
  extern __shared__ char smem[];
  short* act  = (short*)(smem + LDS_ACT);
  short* mbuf = (short*)(smem + LDS_MBUF);
  float* fp   = (float*)(smem + LDS_FP);
  float* dsq  = fp;            // 128
  float* vmask = fp + 128;     // 128
  float* coef = fp + 256;      // 384 (3 x 128)
  unsigned short* cidx16 = (unsigned short*)(smem + LDS_CIDX);
  int* wcnt = (int*)(smem + LDS_WCNT);
  int* wsc  = wcnt + 8;        // [0..7] offsets, [8] = deg

  const int tid  = threadIdx.x;
  const int bi   = blockIdx.x;            // b*384 + i
  const int bb   = (bi / 384) * 384;
  const int wave = tid >> 6;
  const int lane = tid & 63;
  const int g    = lane >> 4;
  const int lr   = lane & 15;
  const int R  = wave * 16;               // GEMM1/GEMM3 d-block of this wave
  const int RB = (wave >> 1) * 32;        // GEMM2 d-rows
  const int CB = (wave & 1) * 64;         // GEMM2 j-slot cols
  const int d4 = R + 4*g;                 // this lane's 4 consecutive d

  // ---- adjacency ballot (wcnt region never overlapped by overlays) ----
  const bool pred = (tid < 384) && (adj[(size_t)bi*384 + tid] != 0);
  const unsigned long long bmask = __ballot(pred);
  if (lane == 0) wcnt[wave] = __popcll(bmask);

  // ---- stage weight overlays (bf16, [out_d][k]) ----
  short* w2o  = (short*)(smem + 0);
  short* wc1o = (short*)(smem + 34816);
  short* weo  = (short*)(smem + 68608);
  for (int idx = tid; idx < 32*128; idx += 512) {
    int k = idx >> 7, d = idx & 127;
    weo[d*40 + k] = (short)f2bf(msg_w1[(size_t)(256 + k)*128 + d]);
  }
  for (int idx = tid; idx < 128*128; idx += 512) {
    int k = idx >> 7, d = idx & 127;
    w2o[d*136 + k]  = (short)f2bf(msg_w2[idx]);
    wc1o[d*132 + k] = (short)f2bf(coord_w1[idx]);
  }
  __syncthreads();

  // ---- scan (tid 0) + move weight fragments to VGPRs ----
  if (tid == 0) {
    int run = 0;
    #pragma unroll
    for (int w = 0; w < 8; ++w) { wsc[w] = run; run += wcnt[w]; }
    wsc[8] = run;
  }
  const u32x4 aw = *(const u32x4*)(weo + (R + lr)*40 + g*8);
  u32x4 w2f0[4], w2f1[4], wc1f[4];
  #pragma unroll
  for (int kk = 0; kk < 4; ++kk) {
    w2f0[kk] = *(const u32x4*)(w2o + (RB + lr)*136 + kk*32 + g*8);
    w2f1[kk] = *(const u32x4*)(w2o + (RB + 16 + lr)*136 + kk*32 + g*8);
    u32x2 lo = *(const u32x2*)(wc1o + (R + lr)*132 + kk*32 + g*8);
    u32x2 hi = *(const u32x2*)(wc1o + (R + lr)*132 + kk*32 + g*8 + 4);
    wc1f[kk] = (u32x4){lo[0], lo[1], hi[0], hi[1]};
  }
  __syncthreads();   // overlays consumed; wsc visible

  // ---- compacted index list + per-lane constants ----
  if (pred) {
    int rank = __popcll(bmask & ((1ull << lane) - 1ull));
    cidx16[wsc[wave] + rank] = (unsigned short)tid;
  }
  const int deg = wsc[8];
  const float4 His4 = *(const float4*)(his + (size_t)bi*128 + d4);
  const float4 wd4  = *(const float4*)(msg_w1 + 288*128 + d4);
  const float4 b2a  = *(const float4*)(msg_b2 + RB + 4*g);
  const float4 b2b  = *(const float4*)(msg_b2 + RB + 16 + 4*g);
  const f32x4  bc1f = *(const f32x4*)(coord_b1 + d4);
  const f32x4  wc2f = *(const f32x4*)(coord_w2 + d4);
  const float xi0 = x[bi*3+0], xi1 = x[bi*3+1], xi2 = x[bi*3+2];
  float hacc_v[8];
  #pragma unroll
  for (int v = 0; v < 8; ++v) hacc_v[v] = 0.0f;
  float xc0 = 0.0f, xc1 = 0.0f, xc2 = 0.0f;
  __syncthreads();   // cidx visible

  const int nchunk = (deg + 127) >> 7;
  for (int ch = 0; ch < nchunk; ++ch) {
    const int j0 = ch * 128;
    // ---- geometry for this chunk (no tile staging needed) ----
    if (tid < 128) {
      int t = j0 + tid;
      int cj = (t < deg) ? (int)cidx16[t] : 0;
      float r0 = xi0 - x[(bb + cj)*3 + 0];
      float r1 = xi1 - x[(bb + cj)*3 + 1];
      float r2 = xi2 - x[(bb + cj)*3 + 2];
      float dq = r0*r0 + r1*r1 + r2*r2;
      float vm = (t < deg) ? 1.0f : 0.0f;
      float fc = __builtin_amdgcn_rcpf(sqrtf(dq + 1e-8f) + 1.0f) * vm;
      dsq[tid] = dq; vmask[tid] = vm;
      coef[tid] = fc*r0; coef[128+tid] = fc*r1; coef[256+tid] = fc*r2;
    }
    __syncthreads();

    // ---- GEMM1: act[j][d] = silu(We^T x eattr_row + (His + Hjs + wd*dsq)) ----
    #pragma unroll
    for (int cf = 0; cf < 8; ++cf) {
      const int j = cf*16 + lr;
      const int t = j0 + j;
      const int cj = (t < deg) ? (int)cidx16[t] : 0;
      const float* ep = eattr + ((size_t)bi*384 + cj)*32 + g*8;
      float4 p0 = ((const float4*)ep)[0];
      float4 p1 = ((const float4*)ep)[1];
      u32x4 be = (u32x4){pk2(p0.x, p0.y), pk2(p0.z, p0.w),
                         pk2(p1.x, p1.y), pk2(p1.z, p1.w)};
      u32x2 hj = *(const u32x2*)(hjw + (size_t)(bb + cj)*128 + d4);
      const float dq = dsq[j];
      f32x4 acc;
      acc[0] = His4.x + dq*wd4.x + bf2f((unsigned short)(hj[0] & 0xFFFFu));
      acc[1] = His4.y + dq*wd4.y + bf2f((unsigned short)(hj[0] >> 16));
      acc[2] = His4.z + dq*wd4.z + bf2f((unsigned short)(hj[1] & 0xFFFFu));
      acc[3] = His4.w + dq*wd4.w + bf2f((unsigned short)(hj[1] >> 16));
      acc = mfma16(aw, be, acc);
      *(u32x2*)(act + j*136 + d4) =
          (u32x2){pk2(silu_f(acc[0]), silu_f(acc[1])),
                  pk2(silu_f(acc[2]), silu_f(acc[3]))};
    }
    __syncthreads();

    // ---- GEMM2: m[j][d] = silu(W2^T x m1_row + b2)*vmask; hacc in-reg ----
    #pragma unroll
    for (int cf = 0; cf < 4; ++cf) {
      const int j = CB + cf*16 + lr;
      f32x4 a0 = (f32x4){b2a.x, b2a.y, b2a.z, b2a.w};
      f32x4 a1 = (f32x4){b2b.x, b2b.y, b2b.z, b2b.w};
      #pragma unroll
      for (int kk = 0; kk < 4; ++kk) {
        u32x4 bfr = *(const u32x4*)(act + j*136 + kk*32 + g*8);
        a0 = mfma16(w2f0[kk], bfr, a0);
        a1 = mfma16(w2f1[kk], bfr, a1);
      }
      const float aj = vmask[j];
      float v0 = silu_f(a0[0]) * aj, v1 = silu_f(a0[1]) * aj;
      float v2 = silu_f(a0[2]) * aj, v3 = silu_f(a0[3]) * aj;
      float w0 = silu_f(a1[0]) * aj, w1 = silu_f(a1[1]) * aj;
      float w2 = silu_f(a1[2]) * aj, w3 = silu_f(a1[3]) * aj;
      hacc_v[0] += v0; hacc_v[1] += v1; hacc_v[2] += v2; hacc_v[3] += v3;
      hacc_v[4] += w0; hacc_v[5] += w1; hacc_v[6] += w2; hacc_v[7] += w3;
      *(u32x2*)(mbuf + j*132 + RB + 4*g)      = (u32x2){pk2(v0, v1), pk2(v2, v3)};
      *(u32x2*)(mbuf + j*132 + RB + 16 + 4*g) = (u32x2){pk2(w0, w1), pk2(w2, w3)};
    }
    __syncthreads();

    // ---- GEMM3: c1[j][d-block R]; cw partial folded into xc via linear coef ----
    #pragma unroll
    for (int cf = 0; cf < 8; ++cf) {
      const int j = cf*16 + lr;
      f32x4 acc3 = bc1f;
      #pragma unroll
      for (int kk = 0; kk < 4; ++kk) {
        u32x2 blo = *(const u32x2*)(mbuf + j*132 + kk*32 + g*8);
        u32x2 bhi = *(const u32x2*)(mbuf + j*132 + kk*32 + g*8 + 4);
        u32x4 bm = (u32x4){blo[0], blo[1], bhi[0], bhi[1]};
        acc3 = mfma16(wc1f[kk], bm, acc3);
      }
      float part = silu_f(acc3[0]) * wc2f[0] + silu_f(acc3[1]) * wc2f[1]
                 + silu_f(acc3[2]) * wc2f[2] + silu_f(acc3[3]) * wc2f[3];
      xc0 += part * coef[j];
      xc1 += part * coef[128 + j];
      xc2 += part * coef[256 + j];
    }
    __syncthreads();
  }

  // ---- tail: reductions ----
  #pragma unroll
  for (int v = 0; v < 8; ++v) {
    hacc_v[v] += __shfl_xor(hacc_v[v], 1, 64);
    hacc_v[v] += __shfl_xor(hacc_v[v], 2, 64);
    hacc_v[v] += __shfl_xor(hacc_v[v], 4, 64);
    hacc_v[v] += __shfl_xor(hacc_v[v], 8, 64);
  }
  #pragma unroll
  for (int mm = 1; mm < 64; mm <<= 1) {
    xc0 += __shfl_xor(xc0, mm, 64);
    xc1 += __shfl_xor(xc1, mm, 64);
    xc2 += __shfl_xor(xc2, mm, 64);
  }
  float* actF  = (float*)act;     // act dead; reuse as f32 scratch
  float* hpart = actF;            // 256
  float* xcw   = actF + 256;      // 24
  float* hagg  = actF + 288;      // 128
  float* hrow  = actF + 416;      // 128
  float* red   = actF + 544;      // 512
  float* uvec  = actF + 1056;     // 128
  float* lnr   = actF + 1184;     // 4
  if (lr == 0) {
    #pragma unroll
    for (int rf = 0; rf < 2; ++rf)
      #pragma unroll
      for (int r = 0; r < 4; ++r)
        hpart[(wave & 1)*128 + RB + rf*16 + 4*g + r] = hacc_v[rf*4 + r];
  }
  if (lane == 0) { xcw[wave*3+0] = xc0; xcw[wave*3+1] = xc1; xcw[wave*3+2] = xc2; }
  if (tid < 128) hrow[tid] = h[(size_t)bi*128 + tid];
  __syncthreads();
  if (tid < 128) hagg[tid] = hpart[tid] + hpart[128 + tid];
  if (tid < 3) {
    float sx = 0.0f;
    #pragma unroll
    for (int w = 0; w < 8; ++w) sx += xcw[w*3 + tid];
    out[98304 + (size_t)bi*3 + tid] = x[bi*3 + tid] + sx * amask[bi];
  }
  __syncthreads();

  // ---- node MLP layer 1: u = silu([h, hagg] @ node_w1 + b1) ----
  {
    const int d = tid & 127, q = tid >> 7;
    float s = 0.0f;
    for (int k = q*64; k < q*64 + 64; ++k) {
      const float inv = (k < 128) ? hrow[k] : hagg[k - 128];
      s += inv * node_w1[(size_t)k*128 + d];
    }
    red[q*128 + d] = s;
  }
  __syncthreads();
  if (tid < 128)
    uvec[tid] = silu_f(red[tid] + red[128+tid] + red[256+tid] + red[384+tid] + node_b1[tid]);
  __syncthreads();

  // ---- node MLP layer 2 + residual ----
  {
    const int d = tid & 127, q = tid >> 7;
    float s = 0.0f;
    for (int k = q*32; k < q*32 + 32; ++k) s += uvec[k] * node_w2[(size_t)k*128 + d];
    red[q*128 + d] = s;
  }
  __syncthreads();
  float y = 0.0f;
  if (tid < 128)
    y = hrow[tid] + red[tid] + red[128+tid] + red[256+tid] + red[384+tid] + node_b2[tid];

  // ---- LayerNorm across 128 values (2 waves active) ----
  float ssum = (tid < 128) ? y : 0.0f;
  #pragma unroll
  for (int mm = 1; mm < 64; mm <<= 1) ssum += __shfl_xor(ssum, mm, 64);
  if (tid < 128 && lane == 0) lnr[wave] = ssum;
  __syncthreads();
  const float mu = (lnr[0] + lnr[1]) * (1.0f/128.0f);
  float yc = (tid < 128) ? (y - mu) : 0.0f;
  float sq = yc * yc;
  #pragma unroll
  for (int mm = 1; mm < 64; mm <<= 1) sq += __shfl_xor(sq, mm, 64);
  if (tid < 128 && lane == 0) lnr[2 + wave] = sq;
  __syncthreads();
  if (tid < 128) {
    const float var = (lnr[2] + lnr[3]) * (1.0f/128.0f);
    out[(size_t)bi*128 + tid] = yc * rsqrtf(var + 1e-3f) * ln_g[tid] + ln_b[tid];
  }
}

extern "C" void kernel_launch(void* const* d_in, const int* in_sizes, int n_in,
                              void* d_out, int out_size, void* d_ws, size_t ws_size,
                              hipStream_t stream) {
  const float* h        = (const float*)d_in[0];
  const float* x        = (const float*)d_in[1];
  const float* eattr    = (const float*)d_in[2];
  const float* amask    = (const float*)d_in[3];
  const float* msg_w1   = (const float*)d_in[4];
  const float* msg_b1   = (const float*)d_in[5];
  const float* msg_w2   = (const float*)d_in[6];
  const float* msg_b2   = (const float*)d_in[7];
  const float* node_w1  = (const float*)d_in[8];
  const float* node_b1  = (const float*)d_in[9];
  const float* node_w2  = (const float*)d_in[10];
  const float* node_b2  = (const float*)d_in[11];
  const float* coord_w1 = (const float*)d_in[12];
  const float* coord_b1 = (const float*)d_in[13];
  const float* coord_w2 = (const float*)d_in[14];
  const float* ln_g     = (const float*)d_in[15];
  const float* ln_b     = (const float*)d_in[16];
  const int*   adj      = (const int*)d_in[17];
  float* out = (float*)d_out;
  float* his = (float*)d_ws;                                        // 768*128*4
  unsigned short* hjw = (unsigned short*)((char*)d_ws + 393216);    // 768*128*2

  hipFuncSetAttribute((const void*)egnn_main,
                      hipFuncAttributeMaxDynamicSharedMemorySize, LDS_BYTES);

  egnn_pre<<<768, 256, 0, stream>>>(h, msg_w1, msg_b1, his, hjw);
  egnn_main<<<768, 512, LDS_BYTES, stream>>>(h, x, eattr, amask, msg_w1, msg_w2,
      msg_b2, node_w1, node_b1, node_w2, node_b2, coord_w1, coord_b1, coord_w2,
      ln_g, ln_b, adj, his, hjw, out);
}

// Round 8
// 91.698 us; speedup vs baseline: 1.6610x; 1.5540x over previous
//
#include <hip/hip_runtime.h>

typedef float f32x4 __attribute__((ext_vector_type(4)));
typedef unsigned int u32x4 __attribute__((ext_vector_type(4)));
typedef unsigned int u32x2 __attribute__((ext_vector_type(2)));
typedef __bf16 bf16x8 __attribute__((ext_vector_type(8)));

// ---------------- LDS layout (bytes) ----------------
#define LDS_WET   0        // [128][40]  bf16 : 10240  (We^T: [d][k], K=32)
#define LDS_W2T   10240    // [128][136] bf16 : 34816  (W2^T: [d][k])
#define LDS_WC1T  45056    // [128][136] bf16 : 34816  (Wc1^T: [d][k])
#define LDS_ACT   79872    // [128][136] bf16 : 34816  (m1 [slot][k]; tail f32 scratch)
#define LDS_MBUF  114688   // [128][132] bf16 : 33792  (Hjs tile -> masked m, [slot][d])
#define LDS_EBUF  148480   // [128][40]  bf16 : 10240  (eattr tile [slot][k])
#define LDS_FP    158720   // 1024 f32 : 4096
// fp floats: dsq 0, vmask 128, coef 256 (384), bc1s 640, wc2s 768, hrow 896
#define LDS_CIDX  162816   // 384 u16 : 768
#define LDS_WCNT  163584   // 17 ints : 68
#define LDS_BYTES 163652   // <= 163840

__device__ __forceinline__ unsigned short f2bf(float f) {
  unsigned int u = __builtin_bit_cast(unsigned int, f);
  unsigned int r = u + 0x7FFFu + ((u >> 16) & 1u);
  return (unsigned short)(r >> 16);
}
__device__ __forceinline__ float bf2f(unsigned short hbits) {
  unsigned int u = ((unsigned int)hbits) << 16;
  return __builtin_bit_cast(float, u);
}
__device__ __forceinline__ unsigned int pk2(float lo, float hi) {
  return (unsigned int)f2bf(lo) | ((unsigned int)f2bf(hi) << 16);
}
__device__ __forceinline__ float silu_f(float xv) {
  float t = __builtin_amdgcn_exp2f(-1.44269504088896f * xv);  // exp(-x)
  return xv * __builtin_amdgcn_rcpf(1.0f + t);
}
__device__ __forceinline__ f32x4 mfma16(u32x4 a, u32x4 b, f32x4 c) {
  return __builtin_amdgcn_mfma_f32_16x16x32_bf16(
      __builtin_bit_cast(bf16x8, a), __builtin_bit_cast(bf16x8, b), c, 0, 0, 0);
}

// ---- precompute: his = h@W1[0:128]+b1 (f32), hjw = bf16(h@W1[128:256]) ----
__global__ void egnn_pre(const float* __restrict__ h,
                         const float* __restrict__ msg_w1,
                         const float* __restrict__ msg_b1,
                         float* __restrict__ his,
                         unsigned short* __restrict__ hjw) {
  __shared__ float hr[128];
  const int row = blockIdx.x;      // b*384+n
  const int t = threadIdx.x;       // 0..255
  if (t < 128) hr[t] = h[(size_t)row*128 + t];
  __syncthreads();
  const int col = t & 127;
  const int base = (t < 128) ? 0 : 128;
  float s = (t < 128) ? msg_b1[col] : 0.0f;
  #pragma unroll 4
  for (int k = 0; k < 128; ++k) s += hr[k] * msg_w1[(size_t)(base + k)*128 + col];
  if (t < 128) his[(size_t)row*128 + col] = s;
  else         hjw[(size_t)row*128 + col] = f2bf(s);
}

// ---------------- fused main kernel: one block per (b,i) ----------------
__launch_bounds__(512, 1)
__global__ void egnn_main(
    const float* __restrict__ h, const float* __restrict__ x,
    const float* __restrict__ eattr, const float* __restrict__ amask,
    const float* __restrict__ msg_w1, const float* __restrict__ msg_w2,
    const float* __restrict__ msg_b2, const float* __restrict__ node_w1,
    const float* __restrict__ node_b1, const float* __restrict__ node_w2,
    const float* __restrict__ node_b2, const float* __restrict__ coord_w1,
    const float* __restrict__ coord_b1, const float* __restrict__ coord_w2,
    const float* __restrict__ ln_g, const float* __restrict__ ln_b,
    const int* __restrict__ adj, const float* __restrict__ his,
    const unsigned short* __restrict__ hjw, float* __restrict__ out)
{
  extern __shared__ char smem[];
  short* weT  = (short*)(smem + LDS_WET);
  short* w2T  = (short*)(smem + LDS_W2T);
  short* wc1T = (short*)(smem + LDS_WC1T);
  short* act  = (short*)(smem + LDS_ACT);
  short* mbuf = (short*)(smem + LDS_MBUF);
  short* ebuf = (short*)(smem + LDS_EBUF);
  float* fp   = (float*)(smem + LDS_FP);
  float* dsq   = fp;         float* vmask = fp + 128;
  float* coef  = fp + 256;   float* bc1s  = fp + 640;
  float* wc2s  = fp + 768;   float* hrow  = fp + 896;
  unsigned short* cidx16 = (unsigned short*)(smem + LDS_CIDX);
  int* wcnt = (int*)(smem + LDS_WCNT);
  int* wsc  = wcnt + 8;      // [0..7] offsets, [8] = deg

  const int tid  = threadIdx.x;
  const int bi   = blockIdx.x;            // b*384 + i
  const int bb   = (bi / 384) * 384;
  const int wave = tid >> 6;
  const int lane = tid & 63;
  const int g    = lane >> 4;
  const int lr   = lane & 15;
  const int R  = wave * 16;               // GEMM1 d-rows / GEMM3 j-slot block
  const int RB = (wave >> 1) * 32;        // GEMM2 d-rows
  const int CB = (wave & 1) * 64;         // GEMM2 j-slot cols
  const int d4 = R + 4*g;                 // GEMM1: this lane's 4 consecutive d
  const int jW = R + lr;                  // GEMM3: this lane's j-slot

  // ---- adjacency ballot ----
  const bool pred = (tid < 384) && (adj[(size_t)bi*384 + tid] != 0);
  const unsigned long long bmask = __ballot(pred);
  if (lane == 0) wcnt[wave] = __popcll(bmask);

  // ---- stage weights (bf16, [out_d][k]) ----
  for (int idx = tid; idx < 32*128; idx += 512) {
    int k = idx >> 7, d = idx & 127;
    weT[d*40 + k] = (short)f2bf(msg_w1[(size_t)(256 + k)*128 + d]);
  }
  for (int idx = tid; idx < 128*128; idx += 512) {
    int k = idx >> 7, d = idx & 127;
    w2T[d*136 + k]  = (short)f2bf(msg_w2[idx]);
    wc1T[d*136 + k] = (short)f2bf(coord_w1[idx]);
  }
  if (tid < 128) {
    bc1s[tid] = coord_b1[tid];
    wc2s[tid] = coord_w2[tid];
    hrow[tid] = h[(size_t)bi*128 + tid];
  }
  __syncthreads();   // weights staged + wcnt visible

  if (tid == 0) {
    int run = 0;
    #pragma unroll
    for (int w = 0; w < 8; ++w) { wsc[w] = run; run += wcnt[w]; }
    wsc[8] = run;
  }
  __syncthreads();   // wsc visible
  if (pred) {
    int rank = __popcll(bmask & ((1ull << lane) - 1ull));
    cidx16[wsc[wave] + rank] = (unsigned short)tid;
  }
  const int deg = wsc[8];
  // per-lane constants (fixed d-ranges across chunks)
  const float4 His4 = *(const float4*)(his + (size_t)bi*128 + d4);
  const float4 wd4  = *(const float4*)(msg_w1 + 288*128 + d4);
  const float4 b2a  = *(const float4*)(msg_b2 + RB + 4*g);
  const float4 b2b  = *(const float4*)(msg_b2 + RB + 16 + 4*g);
  const float xi0 = x[bi*3+0], xi1 = x[bi*3+1], xi2 = x[bi*3+2];
  float hacc_v[8];
  #pragma unroll
  for (int v = 0; v < 8; ++v) hacc_v[v] = 0.0f;
  float xc0 = 0.0f, xc1 = 0.0f, xc2 = 0.0f;
  __syncthreads();   // cidx visible

  const int nchunk = (deg + 127) >> 7;
  for (int ch = 0; ch < nchunk; ++ch) {
    const int j0 = ch * 128;
    // ---- stage: gathered Hjs tile, gathered eattr tile, geometry ----
    #pragma unroll
    for (int it = 0; it < 4; ++it) {
      int idx = tid + it*512;
      int r = idx >> 4, s = idx & 15;
      int t = j0 + r;
      int cj = (t < deg) ? (int)cidx16[t] : 0;
      u32x4 v = *(const u32x4*)(hjw + ((size_t)(bb + cj))*128 + s*8);
      *(u32x2*)(mbuf + r*132 + s*8)     = (u32x2){v[0], v[1]};
      *(u32x2*)(mbuf + r*132 + s*8 + 4) = (u32x2){v[2], v[3]};
    }
    #pragma unroll
    for (int it = 0; it < 2; ++it) {
      int idx = tid + it*512;
      int j = idx >> 3, s = idx & 7;
      int t = j0 + j;
      int cj = (t < deg) ? (int)cidx16[t] : 0;
      float4 p = *(const float4*)(eattr + ((size_t)bi*384 + cj)*32 + s*4);
      *(u32x2*)(ebuf + j*40 + s*4) = (u32x2){pk2(p.x, p.y), pk2(p.z, p.w)};
    }
    if (tid < 128) {
      int t = j0 + tid;
      int cj = (t < deg) ? (int)cidx16[t] : 0;
      float r0 = xi0 - x[(bb + cj)*3 + 0];
      float r1 = xi1 - x[(bb + cj)*3 + 1];
      float r2 = xi2 - x[(bb + cj)*3 + 2];
      float dq = r0*r0 + r1*r1 + r2*r2;
      float vm = (t < deg) ? 1.0f : 0.0f;
      float fc = __builtin_amdgcn_rcpf(sqrtf(dq + 1e-8f) + 1.0f) * vm;
      dsq[tid] = dq; vmask[tid] = vm;
      coef[tid] = fc*r0; coef[128+tid] = fc*r1; coef[256+tid] = fc*r2;
    }
    __syncthreads();

    // ---- GEMM1 (C^T): act[slot][d] = silu(We^T x eattr + init) ----
    {
      u32x4 aw = *(const u32x4*)(weT + (R + lr)*40 + g*8);
      #pragma unroll
      for (int cf = 0; cf < 8; ++cf) {
        const int j = cf*16 + lr;
        u32x4 be = *(const u32x4*)(ebuf + j*40 + g*8);
        u32x2 hj = *(const u32x2*)(mbuf + j*132 + d4);
        const float dq = dsq[j];
        f32x4 acc;
        acc[0] = His4.x + dq*wd4.x + bf2f((unsigned short)(hj[0] & 0xFFFFu));
        acc[1] = His4.y + dq*wd4.y + bf2f((unsigned short)(hj[0] >> 16));
        acc[2] = His4.z + dq*wd4.z + bf2f((unsigned short)(hj[1] & 0xFFFFu));
        acc[3] = His4.w + dq*wd4.w + bf2f((unsigned short)(hj[1] >> 16));
        acc = mfma16(aw, be, acc);
        *(u32x2*)(act + j*136 + d4) =
            (u32x2){pk2(silu_f(acc[0]), silu_f(acc[1])),
                    pk2(silu_f(acc[2]), silu_f(acc[3]))};
      }
    }
    __syncthreads();

    // ---- GEMM2 (C^T): m[slot][d] = silu(W2^T x m1 + b2)*vmask; hacc in-reg ----
    {
      f32x4 acc2[2][4];
      #pragma unroll
      for (int cf = 0; cf < 4; ++cf) {
        acc2[0][cf] = (f32x4){b2a.x, b2a.y, b2a.z, b2a.w};
        acc2[1][cf] = (f32x4){b2b.x, b2b.y, b2b.z, b2b.w};
      }
      #pragma unroll
      for (int kk = 0; kk < 4; ++kk) {
        u32x4 a0 = *(const u32x4*)(w2T + (RB + lr)*136 + kk*32 + g*8);
        u32x4 a1 = *(const u32x4*)(w2T + (RB + 16 + lr)*136 + kk*32 + g*8);
        #pragma unroll
        for (int cf = 0; cf < 4; ++cf) {
          u32x4 bfr = *(const u32x4*)(act + (CB + cf*16 + lr)*136 + kk*32 + g*8);
          acc2[0][cf] = mfma16(a0, bfr, acc2[0][cf]);
          acc2[1][cf] = mfma16(a1, bfr, acc2[1][cf]);
        }
      }
      #pragma unroll
      for (int cf = 0; cf < 4; ++cf) {
        const int j = CB + cf*16 + lr;
        const float aj = vmask[j];
        #pragma unroll
        for (int rf = 0; rf < 2; ++rf) {
          float v0 = silu_f(acc2[rf][cf][0]) * aj;
          float v1 = silu_f(acc2[rf][cf][1]) * aj;
          float v2 = silu_f(acc2[rf][cf][2]) * aj;
          float v3 = silu_f(acc2[rf][cf][3]) * aj;
          hacc_v[rf*4+0] += v0; hacc_v[rf*4+1] += v1;
          hacc_v[rf*4+2] += v2; hacc_v[rf*4+3] += v3;
          *(u32x2*)(mbuf + j*132 + RB + rf*16 + 4*g) =
              (u32x2){pk2(v0, v1), pk2(v2, v3)};
        }
      }
    }
    __syncthreads();

    // ---- GEMM3 (C^T): c1[d][slot]; cw via in-wave g-reduce; xc in-reg ----
    {
      f32x4 acc3[8];
      #pragma unroll
      for (int rf = 0; rf < 8; ++rf)
        acc3[rf] = *(const f32x4*)(bc1s + rf*16 + 4*g);
      #pragma unroll
      for (int kk = 0; kk < 4; ++kk) {
        u32x2 blo = *(const u32x2*)(mbuf + jW*132 + kk*32 + g*8);
        u32x2 bhi = *(const u32x2*)(mbuf + jW*132 + kk*32 + g*8 + 4);
        u32x4 bm = (u32x4){blo[0], blo[1], bhi[0], bhi[1]};
        #pragma unroll
        for (int rf = 0; rf < 8; ++rf) {
          u32x4 af = *(const u32x4*)(wc1T + (rf*16 + lr)*136 + kk*32 + g*8);
          acc3[rf] = mfma16(af, bm, acc3[rf]);
        }
      }
      float cwp = 0.0f;
      #pragma unroll
      for (int rf = 0; rf < 8; ++rf) {
        f32x4 wv = *(const f32x4*)(wc2s + rf*16 + 4*g);
        cwp += silu_f(acc3[rf][0]) * wv[0];
        cwp += silu_f(acc3[rf][1]) * wv[1];
        cwp += silu_f(acc3[rf][2]) * wv[2];
        cwp += silu_f(acc3[rf][3]) * wv[3];
      }
      cwp += __shfl_xor(cwp, 16, 64);
      cwp += __shfl_xor(cwp, 32, 64);
      if (lane < 16) {
        xc0 += cwp * coef[jW];
        xc1 += cwp * coef[128 + jW];
        xc2 += cwp * coef[256 + jW];
      }
    }
    __syncthreads();
  }

  // ---- tail: hacc reduce (shuffle over lr) + xc publish ----
  #pragma unroll
  for (int v = 0; v < 8; ++v) {
    hacc_v[v] += __shfl_xor(hacc_v[v], 1, 64);
    hacc_v[v] += __shfl_xor(hacc_v[v], 2, 64);
    hacc_v[v] += __shfl_xor(hacc_v[v], 4, 64);
    hacc_v[v] += __shfl_xor(hacc_v[v], 8, 64);
  }
  float* actF  = (float*)act;     // act dead; reuse as f32 scratch
  float* hpart = actF;            // 256
  float* xcf   = actF + 256;      // 384
  float* red   = actF + 640;      // 512
  float* hagg  = actF + 1152;     // 128
  float* uvec  = actF + 1280;     // 128
  float* lnr   = actF + 1408;     // 4
  if (lr == 0) {
    #pragma unroll
    for (int rf = 0; rf < 2; ++rf)
      #pragma unroll
      for (int r = 0; r < 4; ++r)
        hpart[(wave & 1)*128 + RB + rf*16 + 4*g + r] = hacc_v[rf*4 + r];
  }
  if (lane < 16) {
    xcf[jW] = xc0; xcf[128 + jW] = xc1; xcf[256 + jW] = xc2;
  }
  __syncthreads();
  if (tid < 128) hagg[tid] = hpart[tid] + hpart[128 + tid];
  if (tid < 3) {
    float sx = 0.0f;
    #pragma unroll 8
    for (int j = 0; j < 128; ++j) sx += xcf[tid*128 + j];
    out[98304 + (size_t)bi*3 + tid] = x[bi*3 + tid] + sx * amask[bi];
  }
  __syncthreads();

  // ---- node MLP layer 1: u = silu([h, hagg] @ node_w1 + b1) ----
  {
    const int d = tid & 127, q = tid >> 7;
    float s = 0.0f;
    for (int k = q*64; k < q*64 + 64; ++k) {
      const float inv = (k < 128) ? hrow[k] : hagg[k - 128];
      s += inv * node_w1[(size_t)k*128 + d];
    }
    red[q*128 + d] = s;
  }
  __syncthreads();
  if (tid < 128)
    uvec[tid] = silu_f(red[tid] + red[128+tid] + red[256+tid] + red[384+tid] + node_b1[tid]);
  __syncthreads();

  // ---- node MLP layer 2 + residual ----
  {
    const int d = tid & 127, q = tid >> 7;
    float s = 0.0f;
    for (int k = q*32; k < q*32 + 32; ++k) s += uvec[k] * node_w2[(size_t)k*128 + d];
    red[q*128 + d] = s;
  }
  __syncthreads();
  float y = 0.0f;
  if (tid < 128)
    y = hrow[tid] + red[tid] + red[128+tid] + red[256+tid] + red[384+tid] + node_b2[tid];

  // ---- LayerNorm across 128 values (2 waves active) ----
  float ssum = (tid < 128) ? y : 0.0f;
  #pragma unroll
  for (int mm = 1; mm < 64; mm <<= 1) ssum += __shfl_xor(ssum, mm, 64);
  if (tid < 128 && lane == 0) lnr[wave] = ssum;
  __syncthreads();
  const float mu = (lnr[0] + lnr[1]) * (1.0f/128.0f);
  float yc = (tid < 128) ? (y - mu) : 0.0f;
  float sq = yc * yc;
  #pragma unroll
  for (int mm = 1; mm < 64; mm <<= 1) sq += __shfl_xor(sq, mm, 64);
  if (tid < 128 && lane == 0) lnr[2 + wave] = sq;
  __syncthreads();
  if (tid < 128) {
    const float var = (lnr[2] + lnr[3]) * (1.0f/128.0f);
    out[(size_t)bi*128 + tid] = yc * rsqrtf(var + 1e-3f) * ln_g[tid] + ln_b[tid];
  }
}

extern "C" void kernel_launch(void* const* d_in, const int* in_sizes, int n_in,
                              void* d_out, int out_size, void* d_ws, size_t ws_size,
                              hipStream_t stream) {
  const float* h        = (const float*)d_in[0];
  const float* x        = (const float*)d_in[1];
  const float* eattr    = (const float*)d_in[2];
  const float* amask    = (const float*)d_in[3];
  const float* msg_w1   = (const float*)d_in[4];
  const float* msg_b1   = (const float*)d_in[5];
  const float* msg_w2   = (const float*)d_in[6];
  const float* msg_b2   = (const float*)d_in[7];
  const float* node_w1  = (const float*)d_in[8];
  const float* node_b1  = (const float*)d_in[9];
  const float* node_w2  = (const float*)d_in[10];
  const float* node_b2  = (const float*)d_in[11];
  const float* coord_w1 = (const float*)d_in[12];
  const float* coord_b1 = (const float*)d_in[13];
  const float* coord_w2 = (const float*)d_in[14];
  const float* ln_g     = (const float*)d_in[15];
  const float* ln_b     = (const float*)d_in[16];
  const int*   adj      = (const int*)d_in[17];
  float* out = (float*)d_out;
  float* his = (float*)d_ws;                                        // 768*128*4
  unsigned short* hjw = (unsigned short*)((char*)d_ws + 393216);    // 768*128*2

  hipFuncSetAttribute((const void*)egnn_main,
                      hipFuncAttributeMaxDynamicSharedMemorySize, LDS_BYTES);

  egnn_pre<<<768, 256, 0, stream>>>(h, msg_w1, msg_b1, his, hjw);
  egnn_main<<<768, 512, LDS_BYTES, stream>>>(h, x, eattr, amask, msg_w1, msg_w2,
      msg_b2, node_w1, node_b1, node_w2, node_b2, coord_w1, coord_b1, coord_w2,
      ln_g, ln_b, adj, his, hjw, out);
}

// Round 9
// 87.554 us; speedup vs baseline: 1.7396x; 1.0473x over previous
//
#include <hip/hip_runtime.h>

typedef float f32x4 __attribute__((ext_vector_type(4)));
typedef unsigned int u32x4 __attribute__((ext_vector_type(4)));
typedef unsigned int u32x2 __attribute__((ext_vector_type(2)));
typedef __bf16 bf16x8 __attribute__((ext_vector_type(8)));

// ---------------- LDS layout (bytes) ----------------
#define LDS_WET   0        // [128][40]  bf16 : 10240  (We^T [d][k], K=32)
#define LDS_W2T   10240    // [128][136] bf16 : 34816  (W2^T [d][k])
#define LDS_WC1T  45056    // [128][136] bf16 : 34816  (Wc1^T [d][k])
#define LDS_ACTW  79872    // 8 x [16][136] bf16 : 34816 (wave-local m1; tail f32 scratch)
#define LDS_MBUFW 114688   // 8 x [16][132] bf16 : 33792 (wave-local m)
#define LDS_FP    148480   // 768 f32 : 3072 (His 0, wd 128, b2 256, bc1 384, wc2 512, hrow 640)
#define LDS_CIDX  151552   // 384 u16 : 768
#define LDS_WCNT  152320   // 17 int : 68
#define LDS_BYTES 152388   // <= 163840

__device__ __forceinline__ unsigned short f2bf(float f) {
  unsigned int u = __builtin_bit_cast(unsigned int, f);
  unsigned int r = u + 0x7FFFu + ((u >> 16) & 1u);
  return (unsigned short)(r >> 16);
}
__device__ __forceinline__ float bf2f(unsigned short hbits) {
  unsigned int u = ((unsigned int)hbits) << 16;
  return __builtin_bit_cast(float, u);
}
__device__ __forceinline__ unsigned int pk2(float lo, float hi) {
  return (unsigned int)f2bf(lo) | ((unsigned int)f2bf(hi) << 16);
}
__device__ __forceinline__ float silu_f(float xv) {
  float t = __builtin_amdgcn_exp2f(-1.44269504088896f * xv);  // exp(-x)
  return xv * __builtin_amdgcn_rcpf(1.0f + t);
}
__device__ __forceinline__ f32x4 mfma16(u32x4 a, u32x4 b, f32x4 c) {
  return __builtin_amdgcn_mfma_f32_16x16x32_bf16(
      __builtin_bit_cast(bf16x8, a), __builtin_bit_cast(bf16x8, b), c, 0, 0, 0);
}

// ---- precompute: his = h@W1[0:128]+b1 (f32), hjw = bf16(h@W1[128:256]) ----
__global__ void egnn_pre(const float* __restrict__ h,
                         const float* __restrict__ msg_w1,
                         const float* __restrict__ msg_b1,
                         float* __restrict__ his,
                         unsigned short* __restrict__ hjw) {
  __shared__ float hr[128];
  const int row = blockIdx.x;      // b*384+n
  const int t = threadIdx.x;       // 0..255
  if (t < 128) hr[t] = h[(size_t)row*128 + t];
  __syncthreads();
  const int col = t & 127;
  const int base = (t < 128) ? 0 : 128;
  float s = (t < 128) ? msg_b1[col] : 0.0f;
  #pragma unroll 4
  for (int k = 0; k < 128; ++k) s += hr[k] * msg_w1[(size_t)(base + k)*128 + col];
  if (t < 128) his[(size_t)row*128 + col] = s;
  else         hjw[(size_t)row*128 + col] = f2bf(s);
}

// ---------------- fused main kernel: one block per (b,i) ----------------
__launch_bounds__(512, 1)
__global__ void egnn_main(
    const float* __restrict__ h, const float* __restrict__ x,
    const float* __restrict__ eattr, const float* __restrict__ amask,
    const float* __restrict__ msg_w1, const float* __restrict__ msg_w2,
    const float* __restrict__ msg_b2, const float* __restrict__ node_w1,
    const float* __restrict__ node_b1, const float* __restrict__ node_w2,
    const float* __restrict__ node_b2, const float* __restrict__ coord_w1,
    const float* __restrict__ coord_b1, const float* __restrict__ coord_w2,
    const float* __restrict__ ln_g, const float* __restrict__ ln_b,
    const int* __restrict__ adj, const float* __restrict__ his,
    const unsigned short* __restrict__ hjw, float* __restrict__ out)
{
  extern __shared__ char smem[];
  short* weT  = (short*)(smem + LDS_WET);
  short* w2T  = (short*)(smem + LDS_W2T);
  short* wc1T = (short*)(smem + LDS_WC1T);
  float* fp   = (float*)(smem + LDS_FP);
  float* HisL = fp;          float* wdL  = fp + 128;
  float* b2L  = fp + 256;    float* bc1L = fp + 384;
  float* wc2L = fp + 512;    float* hrow = fp + 640;
  unsigned short* cidx16 = (unsigned short*)(smem + LDS_CIDX);
  int* wcnt = (int*)(smem + LDS_WCNT);
  int* wsc  = wcnt + 8;      // [0..7] offsets, [8] = deg

  const int tid  = threadIdx.x;
  const int bi   = blockIdx.x;            // b*384 + i
  const int bb   = (bi / 384) * 384;
  const int wave = tid >> 6;
  const int lane = tid & 63;
  const int g    = lane >> 4;
  const int lr   = lane & 15;
  short* actW = (short*)(smem + LDS_ACTW) + wave*16*136;   // wave-local [16 j][136]
  short* mbW  = (short*)(smem + LDS_MBUFW) + wave*16*132;  // wave-local [16 j][132]

  // ---- adjacency ballot ----
  const bool pred = (tid < 384) && (adj[(size_t)bi*384 + tid] != 0);
  const unsigned long long bmask = __ballot(pred);
  if (lane == 0) wcnt[wave] = __popcll(bmask);

  // ---- stage weights (bf16, [out_d][k]) + small f32 constants ----
  for (int idx = tid; idx < 32*128; idx += 512) {
    int k = idx >> 7, d = idx & 127;
    weT[d*40 + k] = (short)f2bf(msg_w1[(size_t)(256 + k)*128 + d]);
  }
  for (int idx = tid; idx < 128*128; idx += 512) {
    int k = idx >> 7, d = idx & 127;
    w2T[d*136 + k]  = (short)f2bf(msg_w2[idx]);
    wc1T[d*136 + k] = (short)f2bf(coord_w1[idx]);
  }
  if (tid < 128) {
    HisL[tid] = his[(size_t)bi*128 + tid];
    wdL[tid]  = msg_w1[288*128 + tid];
    b2L[tid]  = msg_b2[tid];
    bc1L[tid] = coord_b1[tid];
    wc2L[tid] = coord_w2[tid];
    hrow[tid] = h[(size_t)bi*128 + tid];
  }
  __syncthreads();   // weights + constants staged, wcnt visible

  if (tid == 0) {
    int run = 0;
    #pragma unroll
    for (int w = 0; w < 8; ++w) { wsc[w] = run; run += wcnt[w]; }
    wsc[8] = run;
  }
  __syncthreads();   // wsc visible
  if (pred) {
    int rank = __popcll(bmask & ((1ull << lane) - 1ull));
    cidx16[wsc[wave] + rank] = (unsigned short)tid;
  }
  const int deg = wsc[8];
  const float xi0 = x[bi*3+0], xi1 = x[bi*3+1], xi2 = x[bi*3+2];
  f32x4 hacc2[8];
  #pragma unroll
  for (int cf = 0; cf < 8; ++cf) hacc2[cf] = (f32x4){0.f, 0.f, 0.f, 0.f};
  float xc0 = 0.0f, xc1 = 0.0f, xc2 = 0.0f;
  __syncthreads();   // cidx visible

  // ======== barrier-free chunk loop: wave owns slots ch*128 + wave*16 + lr ========
  const int nchunk = (deg + 127) >> 7;
  for (int ch = 0; ch < nchunk; ++ch) {
    const int s = ch*128 + wave*16 + lr;
    const bool valid = (s < deg);
    const int cj = valid ? (int)cidx16[s] : 0;
    const float vm = valid ? 1.0f : 0.0f;
    // geometry (per-lane registers; redundant across g)
    const float* xp = x + (size_t)(bb + cj)*3;
    const float r0 = xi0 - xp[0], r1 = xi1 - xp[1], r2 = xi2 - xp[2];
    const float dq = r0*r0 + r1*r1 + r2*r2;
    const float fc = __builtin_amdgcn_rcpf(sqrtf(dq + 1e-8f) + 1.0f) * vm;
    const float c0 = fc*r0, c1 = fc*r1, c2 = fc*r2;
    // eattr B-frag: this lane's j-row, k = g*8..g*8+7
    const float* ep = eattr + ((size_t)bi*384 + cj)*32 + g*8;
    const float4 p0 = ((const float4*)ep)[0];
    const float4 p1 = ((const float4*)ep)[1];
    const u32x4 be = (u32x4){pk2(p0.x, p0.y), pk2(p0.z, p0.w),
                             pk2(p1.x, p1.y), pk2(p1.z, p1.w)};

    // ---- GEMM1: m1[j=lr][d] for all 128 d; acc-init = His + wd*dsq + Hjs ----
    #pragma unroll
    for (int cf = 0; cf < 8; ++cf) {
      const int dO = cf*16 + 4*g;
      u32x2 hj = *(const u32x2*)(hjw + (size_t)(bb + cj)*128 + dO);
      f32x4 hv = *(const f32x4*)(HisL + dO);
      f32x4 wv = *(const f32x4*)(wdL + dO);
      f32x4 acc;
      acc[0] = hv[0] + dq*wv[0] + bf2f((unsigned short)(hj[0] & 0xFFFFu));
      acc[1] = hv[1] + dq*wv[1] + bf2f((unsigned short)(hj[0] >> 16));
      acc[2] = hv[2] + dq*wv[2] + bf2f((unsigned short)(hj[1] & 0xFFFFu));
      acc[3] = hv[3] + dq*wv[3] + bf2f((unsigned short)(hj[1] >> 16));
      u32x4 aw = *(const u32x4*)(weT + (cf*16 + lr)*40 + g*8);
      acc = mfma16(aw, be, acc);
      *(u32x2*)(actW + lr*136 + dO) =
          (u32x2){pk2(silu_f(acc[0]), silu_f(acc[1])),
                  pk2(silu_f(acc[2]), silu_f(acc[3]))};
    }

    // ---- GEMM2: m[j=lr][d] = silu(W2^T · m1_row + b2)*vm; hacc in-reg ----
    u32x4 bk[4];
    #pragma unroll
    for (int kk = 0; kk < 4; ++kk)
      bk[kk] = *(const u32x4*)(actW + lr*136 + kk*32 + g*8);
    #pragma unroll
    for (int cf = 0; cf < 8; ++cf) {
      const int dO = cf*16 + 4*g;
      f32x4 a = *(const f32x4*)(b2L + dO);
      #pragma unroll
      for (int kk = 0; kk < 4; ++kk) {
        u32x4 aw2 = *(const u32x4*)(w2T + (cf*16 + lr)*136 + kk*32 + g*8);
        a = mfma16(aw2, bk[kk], a);
      }
      float v0 = silu_f(a[0]) * vm, v1 = silu_f(a[1]) * vm;
      float v2 = silu_f(a[2]) * vm, v3 = silu_f(a[3]) * vm;
      hacc2[cf][0] += v0; hacc2[cf][1] += v1;
      hacc2[cf][2] += v2; hacc2[cf][3] += v3;
      *(u32x2*)(mbW + lr*132 + dO) = (u32x2){pk2(v0, v1), pk2(v2, v3)};
    }

    // ---- GEMM3: c1[d2][j=lr]; cw = sum_d2 silu(c1)*wc2; fold into xc ----
    u32x4 bm[4];
    #pragma unroll
    for (int kk = 0; kk < 4; ++kk) {
      u32x2 lo = *(const u32x2*)(mbW + lr*132 + kk*32 + g*8);
      u32x2 hi = *(const u32x2*)(mbW + lr*132 + kk*32 + g*8 + 4);
      bm[kk] = (u32x4){lo[0], lo[1], hi[0], hi[1]};
    }
    float cwp = 0.0f;
    #pragma unroll
    for (int cf = 0; cf < 8; ++cf) {
      const int dO = cf*16 + 4*g;
      f32x4 a = *(const f32x4*)(bc1L + dO);
      #pragma unroll
      for (int kk = 0; kk < 4; ++kk) {
        u32x4 aw3 = *(const u32x4*)(wc1T + (cf*16 + lr)*136 + kk*32 + g*8);
        a = mfma16(aw3, bm[kk], a);
      }
      f32x4 wv = *(const f32x4*)(wc2L + dO);
      cwp += silu_f(a[0])*wv[0] + silu_f(a[1])*wv[1]
           + silu_f(a[2])*wv[2] + silu_f(a[3])*wv[3];
    }
    cwp += __shfl_xor(cwp, 16, 64);
    cwp += __shfl_xor(cwp, 32, 64);
    if (lane < 16) { xc0 += cwp*c0; xc1 += cwp*c1; xc2 += cwp*c2; }
  }

  // ======== tail ========
  __syncthreads();   // chunk loop done; safe to reuse actW region
  // reduce hacc over the 16 lr-lanes (sum over this wave's j's)
  #pragma unroll
  for (int cf = 0; cf < 8; ++cf) {
    #pragma unroll
    for (int r = 0; r < 4; ++r) {
      float v = hacc2[cf][r];
      v += __shfl_xor(v, 1, 64); v += __shfl_xor(v, 2, 64);
      v += __shfl_xor(v, 4, 64); v += __shfl_xor(v, 8, 64);
      hacc2[cf][r] = v;
    }
  }
  float* actF  = (float*)(smem + LDS_ACTW);  // f32 scratch over dead actW/mbufW
  float* hpart = actF;            // 8 x 128
  float* xcf   = actF + 1024;     // 384
  float* red   = actF + 1408;     // 512
  float* hagg  = actF + 1920;     // 128
  float* uvec  = actF + 2048;     // 128
  float* lnr   = actF + 2176;     // 4
  if (lr == 0) {
    #pragma unroll
    for (int cf = 0; cf < 8; ++cf)
      #pragma unroll
      for (int r = 0; r < 4; ++r)
        hpart[wave*128 + cf*16 + 4*g + r] = hacc2[cf][r];
  }
  if (lane < 16) {
    const int idx = wave*16 + lr;
    xcf[idx] = xc0; xcf[128 + idx] = xc1; xcf[256 + idx] = xc2;
  }
  __syncthreads();
  if (tid < 128) {
    float s = 0.0f;
    #pragma unroll
    for (int w = 0; w < 8; ++w) s += hpart[w*128 + tid];
    hagg[tid] = s;
  }
  if (tid < 3) {
    float sx = 0.0f;
    #pragma unroll 8
    for (int j = 0; j < 128; ++j) sx += xcf[tid*128 + j];
    out[98304 + (size_t)bi*3 + tid] = x[bi*3 + tid] + sx * amask[bi];
  }
  __syncthreads();

  // ---- node MLP layer 1: u = silu([h, hagg] @ node_w1 + b1) ----
  {
    const int d = tid & 127, q = tid >> 7;
    float s = 0.0f;
    for (int k = q*64; k < q*64 + 64; ++k) {
      const float inv = (k < 128) ? hrow[k] : hagg[k - 128];
      s += inv * node_w1[(size_t)k*128 + d];
    }
    red[q*128 + d] = s;
  }
  __syncthreads();
  if (tid < 128)
    uvec[tid] = silu_f(red[tid] + red[128+tid] + red[256+tid] + red[384+tid] + node_b1[tid]);
  __syncthreads();

  // ---- node MLP layer 2 + residual ----
  {
    const int d = tid & 127, q = tid >> 7;
    float s = 0.0f;
    for (int k = q*32; k < q*32 + 32; ++k) s += uvec[k] * node_w2[(size_t)k*128 + d];
    red[q*128 + d] = s;
  }
  __syncthreads();
  float y = 0.0f;
  if (tid < 128)
    y = hrow[tid] + red[tid] + red[128+tid] + red[256+tid] + red[384+tid] + node_b2[tid];

  // ---- LayerNorm across 128 values (2 waves active) ----
  float ssum = (tid < 128) ? y : 0.0f;
  #pragma unroll
  for (int mm = 1; mm < 64; mm <<= 1) ssum += __shfl_xor(ssum, mm, 64);
  if (tid < 128 && lane == 0) lnr[wave] = ssum;
  __syncthreads();
  const float mu = (lnr[0] + lnr[1]) * (1.0f/128.0f);
  float yc = (tid < 128) ? (y - mu) : 0.0f;
  float sq = yc * yc;
  #pragma unroll
  for (int mm = 1; mm < 64; mm <<= 1) sq += __shfl_xor(sq, mm, 64);
  if (tid < 128 && lane == 0) lnr[2 + wave] = sq;
  __syncthreads();
  if (tid < 128) {
    const float var = (lnr[2] + lnr[3]) * (1.0f/128.0f);
    out[(size_t)bi*128 + tid] = yc * rsqrtf(var + 1e-3f) * ln_g[tid] + ln_b[tid];
  }
}

extern "C" void kernel_launch(void* const* d_in, const int* in_sizes, int n_in,
                              void* d_out, int out_size, void* d_ws, size_t ws_size,
                              hipStream_t stream) {
  const float* h        = (const float*)d_in[0];
  const float* x        = (const float*)d_in[1];
  const float* eattr    = (const float*)d_in[2];
  const float* amask    = (const float*)d_in[3];
  const float* msg_w1   = (const float*)d_in[4];
  const float* msg_b1   = (const float*)d_in[5];
  const float* msg_w2   = (const float*)d_in[6];
  const float* msg_b2   = (const float*)d_in[7];
  const float* node_w1  = (const float*)d_in[8];
  const float* node_b1  = (const float*)d_in[9];
  const float* node_w2  = (const float*)d_in[10];
  const float* node_b2  = (const float*)d_in[11];
  const float* coord_w1 = (const float*)d_in[12];
  const float* coord_b1 = (const float*)d_in[13];
  const float* coord_w2 = (const float*)d_in[14];
  const float* ln_g     = (const float*)d_in[15];
  const float* ln_b     = (const float*)d_in[16];
  const int*   adj      = (const int*)d_in[17];
  float* out = (float*)d_out;
  float* his = (float*)d_ws;                                        // 768*128*4
  unsigned short* hjw = (unsigned short*)((char*)d_ws + 393216);    // 768*128*2

  hipFuncSetAttribute((const void*)egnn_main,
                      hipFuncAttributeMaxDynamicSharedMemorySize, LDS_BYTES);

  egnn_pre<<<768, 256, 0, stream>>>(h, msg_w1, msg_b1, his, hjw);
  egnn_main<<<768, 512, LDS_BYTES, stream>>>(h, x, eattr, amask, msg_w1, msg_w2,
      msg_b2, node_w1, node_b1, node_w2, node_b2, coord_w1, coord_b1, coord_w2,
      ln_g, ln_b, adj, his, hjw, out);
}